// Round 1
// baseline (324.361 us; speedup 1.0000x reference)
//
#include <hip/hip_runtime.h>
#include <hip/hip_bf16.h>
#include <stdint.h>

typedef unsigned short u16;
typedef __attribute__((ext_vector_type(8))) unsigned short u16x8;
typedef __attribute__((ext_vector_type(4))) unsigned short u16x4;
typedef __attribute__((ext_vector_type(8))) __bf16 bf16x8;
typedef __attribute__((ext_vector_type(4))) float f32x4;

// ---------- helpers ----------
__device__ __forceinline__ f32x4 mfma16(u16x8 a, u16x8 b, f32x4 c) {
  return __builtin_amdgcn_mfma_f32_16x16x32_bf16(
      __builtin_bit_cast(bf16x8, a), __builtin_bit_cast(bf16x8, b), c, 0, 0, 0);
}

__device__ __forceinline__ u16 f2bf(float f) {
  unsigned u = __builtin_bit_cast(unsigned, f);
  return (u16)((u + 0x7fffu + ((u >> 16) & 1u)) >> 16);
}

__device__ __forceinline__ void gload_lds16(const void* g, void* l) {
  __builtin_amdgcn_global_load_lds(
      (__attribute__((address_space(1))) void*)const_cast<void*>(g),
      (__attribute__((address_space(3))) void*)l, 16, 0, 0);
}

// ---------- fp32 -> bf16 cast ----------
__global__ void cast_f32_bf16(const float* __restrict__ src, u16* __restrict__ dst, int n4) {
  int i = blockIdx.x * blockDim.x + threadIdx.x;
  if (i < n4) {
    f32x4 v = ((const f32x4*)src)[i];
    u16x4 o;
    o[0] = f2bf(v[0]); o[1] = f2bf(v[1]); o[2] = f2bf(v[2]); o[3] = f2bf(v[3]);
    ((u16x4*)dst)[i] = o;
  }
}

// ---------- fused QKV GEMM ----------
// A: Xb [4096][1024] bf16.  Bm: Wcat [3072][1024] bf16 (rows = output features; y = x @ W^T).
// Output: Q/K/V bf16 in [B=2][H=16][S=2048][Dh=64] layout; Q pre-scaled by 0.125.
__global__ __launch_bounds__(256) void gemm_qkv(
    const u16* __restrict__ A, const u16* __restrict__ Bm,
    const float* __restrict__ bq, const float* __restrict__ bk, const float* __restrict__ bv,
    u16* __restrict__ Qb, u16* __restrict__ Kb, u16* __restrict__ Vb) {
  __shared__ __align__(16) u16 Asm[128 * 32];
  __shared__ __align__(16) u16 Bsm[128 * 32];
  const int tid = threadIdx.x;
  const int wave = tid >> 6, lane = tid & 63;
  const int lq = lane & 15, lg = lane >> 4;
  const int wr = wave >> 1, wc = wave & 1;
  const int m0 = blockIdx.y * 128, n0 = blockIdx.x * 128;

  f32x4 zero = {0.f, 0.f, 0.f, 0.f};
  f32x4 acc[4][4];
#pragma unroll
  for (int mi = 0; mi < 4; ++mi)
#pragma unroll
    for (int ni = 0; ni < 4; ++ni) acc[mi][ni] = zero;

  for (int kt = 0; kt < 32; ++kt) {
    const int k0 = kt * 32;
    __syncthreads();
#pragma unroll
    for (int c = 0; c < 2; ++c) {
      const int idx = wave * 2 + c;  // 0..7, covers 16 rows each
      const u16* ga = A + (size_t)(m0 + idx * 16 + (lane >> 2)) * 1024 + k0 + (lane & 3) * 8;
      gload_lds16(ga, (char*)Asm + idx * 1024);
      const u16* gb = Bm + (size_t)(n0 + idx * 16 + (lane >> 2)) * 1024 + k0 + (lane & 3) * 8;
      gload_lds16(gb, (char*)Bsm + idx * 1024);
    }
    __syncthreads();

    u16x8 af[4], bfr[4];
#pragma unroll
    for (int mi = 0; mi < 4; ++mi)
      af[mi] = *(const u16x8*)&Asm[(wr * 64 + mi * 16 + lq) * 32 + lg * 8];
#pragma unroll
    for (int ni = 0; ni < 4; ++ni)
      bfr[ni] = *(const u16x8*)&Bsm[(wc * 64 + ni * 16 + lq) * 32 + lg * 8];
#pragma unroll
    for (int mi = 0; mi < 4; ++mi)
#pragma unroll
      for (int ni = 0; ni < 4; ++ni)
        acc[mi][ni] = mfma16(af[mi], bfr[ni], acc[mi][ni]);
  }

  // epilogue: bias, Q-scale, scatter to [B,H,S,Dh] bf16
  const int which = n0 >> 10;  // uniform per block (128 | 1024)
  const float* bias = (which == 0) ? bq : ((which == 1) ? bk : bv);
  u16* dst = (which == 0) ? Qb : ((which == 1) ? Kb : Vb);
  const float scl = (which == 0) ? 0.125f : 1.0f;
#pragma unroll
  for (int mi = 0; mi < 4; ++mi) {
    const int m = m0 + wr * 64 + mi * 16 + lg * 4;
    const int bb = m >> 11;
    const int s = m & 2047;
#pragma unroll
    for (int ni = 0; ni < 4; ++ni) {
      const int n = n0 + wc * 64 + ni * 16 + lq;
      const int d = n & 1023;
      const int h = d >> 6, dh = d & 63;
      const float bi = bias[d];
#pragma unroll
      for (int r = 0; r < 4; ++r) {
        float v = (acc[mi][ni][r] + bi) * scl;
        dst[(((size_t)bb * 16 + h) * 2048 + (size_t)(s + r)) * 64 + dh] = f2bf(v);
      }
    }
  }
}

// ---------- attention ----------
// Grid: (32 q-tiles, 32 b*h). Block 256 = 4 waves; wave w owns q rows [q0+16w, q0+16w+16).
// Two passes over K: pass1 -> exact (m,l) per q row; pass2 -> exact probs, PV, colsums.
#define SWZ(row, colbyte) ((((row) * 128) + (colbyte)) ^ (((row) & 7) << 4))

__global__ __launch_bounds__(256) void attn_kernel(
    const u16* __restrict__ Qb, const u16* __restrict__ Kb, const u16* __restrict__ Vb,
    const float* __restrict__ maskg, float* __restrict__ out_ctx, float* __restrict__ out_cs) {
  __shared__ __align__(16) u16 K_lds[64 * 64];
  __shared__ __align__(16) u16 VT_lds[64 * 64];
  __shared__ __align__(16) u16 P_lds[64 * 64];
  __shared__ __align__(16) float mask_lds[2048];
  __shared__ __align__(16) float cs_lds[2048];

  const int tid = threadIdx.x;
  const int wave = tid >> 6, lane = tid & 63;
  const int lq = lane & 15, lg = lane >> 4;
  const int bh = blockIdx.y;
  const int b = bh >> 4, h = bh & 15;
  const int q0 = blockIdx.x * 64;

  for (int i = tid; i < 2048; i += 256) {
    mask_lds[i] = maskg[b * 2048 + i];
    cs_lds[i] = 0.f;
  }

  // Q fragments (B-operand of swapped QK^T): lane holds Q[q=lane&15][dh=8*lg+j (+32)]
  const u16* qp = Qb + ((size_t)bh * 2048 + q0 + wave * 16 + lq) * 64 + lg * 8;
  const u16x8 qa0 = *(const u16x8*)qp;
  const u16x8 qa1 = *(const u16x8*)(qp + 32);

  const u16* Kbase = Kb + (size_t)bh * 2048 * 64;
  const u16* Vbase = Vb + (size_t)bh * 2048 * 64;

  float m_l = -3.0e38f, l_l = 0.f;

  // ---- pass 1: row max + denominator ----
  for (int kt = 0; kt < 32; ++kt) {
    __syncthreads();
    for (int i = tid; i < 512; i += 256) {
      const int row = i >> 3, c8 = (i & 7) * 8;
      u16x8 kv = *(const u16x8*)(Kbase + (size_t)(kt * 64 + row) * 64 + c8);
      *(u16x8*)((char*)K_lds + SWZ(row, c8 * 2)) = kv;
    }
    __syncthreads();
#pragma unroll
    for (int chunk = 0; chunk < 4; ++chunk) {
      const int krow = chunk * 16 + lq;
      u16x8 ka0 = *(const u16x8*)((char*)K_lds + SWZ(krow, lg * 16));
      u16x8 ka1 = *(const u16x8*)((char*)K_lds + SWZ(krow, 64 + lg * 16));
      f32x4 s = {0.f, 0.f, 0.f, 0.f};
      s = mfma16(ka0, qa0, s);  // S^T[kr][q]: col(lane&15)=q, row(lg*4+r)=kr
      s = mfma16(ka1, qa1, s);
      f32x4 mv = *(const f32x4*)&mask_lds[kt * 64 + chunk * 16 + lg * 4];
      const float s0 = s[0] + mv[0], s1 = s[1] + mv[1];
      const float s2 = s[2] + mv[2], s3 = s[3] + mv[3];
      const float cmax = fmaxf(fmaxf(s0, s1), fmaxf(s2, s3));
      const float mn = fmaxf(m_l, cmax);
      l_l = l_l * __expf(m_l - mn) +
            __expf(s0 - mn) + __expf(s1 - mn) + __expf(s2 - mn) + __expf(s3 - mn);
      m_l = mn;
    }
  }
  // merge (m,l) across the 4 lane-groups sharing q = lane&15
#pragma unroll
  for (int off = 16; off <= 32; off <<= 1) {
    const float mo = __shfl_xor(m_l, off);
    const float lo = __shfl_xor(l_l, off);
    const float mn = fmaxf(m_l, mo);
    l_l = l_l * __expf(m_l - mn) + lo * __expf(mo - mn);
    m_l = mn;
  }
  const float inv_l = 1.0f / l_l;

  // ---- pass 2: exact probs -> colsum + PV ----
  f32x4 acc[4];
  {
    f32x4 zero = {0.f, 0.f, 0.f, 0.f};
#pragma unroll
    for (int ni = 0; ni < 4; ++ni) acc[ni] = zero;
  }

  for (int kt = 0; kt < 32; ++kt) {
    __syncthreads();
    for (int i = tid; i < 512; i += 256) {
      const int row = i >> 3, c8 = (i & 7) * 8;
      u16x8 kv = *(const u16x8*)(Kbase + (size_t)(kt * 64 + row) * 64 + c8);
      *(u16x8*)((char*)K_lds + SWZ(row, c8 * 2)) = kv;
      u16x8 vv = *(const u16x8*)(Vbase + (size_t)(kt * 64 + row) * 64 + c8);
#pragma unroll
      for (int j = 0; j < 8; ++j) {  // transpose: VT[dh][k] = V[k][dh]
        const int dh = c8 + j;
        *(u16*)((char*)VT_lds + SWZ(dh, row * 2)) = vv[j];
      }
    }
    __syncthreads();

#pragma unroll
    for (int chunk = 0; chunk < 4; ++chunk) {
      const int krow = chunk * 16 + lq;
      u16x8 ka0 = *(const u16x8*)((char*)K_lds + SWZ(krow, lg * 16));
      u16x8 ka1 = *(const u16x8*)((char*)K_lds + SWZ(krow, 64 + lg * 16));
      f32x4 s = {0.f, 0.f, 0.f, 0.f};
      s = mfma16(ka0, qa0, s);
      s = mfma16(ka1, qa1, s);
      f32x4 mv = *(const f32x4*)&mask_lds[kt * 64 + chunk * 16 + lg * 4];
      float p0 = __expf(s[0] + mv[0] - m_l) * inv_l;
      float p1 = __expf(s[1] + mv[1] - m_l) * inv_l;
      float p2 = __expf(s[2] + mv[2] - m_l) * inv_l;
      float p3 = __expf(s[3] + mv[3] - m_l) * inv_l;

      // column sums over the 16 q lanes (bits 0-3)
      float c0 = p0, c1 = p1, c2 = p2, c3 = p3;
#pragma unroll
      for (int msk = 1; msk <= 8; msk <<= 1) {
        c0 += __shfl_xor(c0, msk);
        c1 += __shfl_xor(c1, msk);
        c2 += __shfl_xor(c2, msk);
        c3 += __shfl_xor(c3, msk);
      }
      if (lq == 0) {
        const int kb = kt * 64 + chunk * 16 + lg * 4;
        atomicAdd(&cs_lds[kb + 0], c0);
        atomicAdd(&cs_lds[kb + 1], c1);
        atomicAdd(&cs_lds[kb + 2], c2);
        atomicAdd(&cs_lds[kb + 3], c3);
      }

      u16x4 pb;
      pb[0] = f2bf(p0); pb[1] = f2bf(p1); pb[2] = f2bf(p2); pb[3] = f2bf(p3);
      const int prow = wave * 16 + lq;
      *(u16x4*)((char*)P_lds + SWZ(prow, chunk * 32 + lg * 8)) = pb;
    }

    // PV: context[q][dh] += P[q][k] * V[k][dh]
#pragma unroll
    for (int kc = 0; kc < 2; ++kc) {
      const int prow = wave * 16 + lq;
      u16x8 pa = *(const u16x8*)((char*)P_lds + SWZ(prow, kc * 64 + lg * 16));
#pragma unroll
      for (int ni = 0; ni < 4; ++ni) {
        const int vrow = ni * 16 + lq;
        u16x8 vb = *(const u16x8*)((char*)VT_lds + SWZ(vrow, kc * 64 + lg * 16));
        acc[ni] = mfma16(pa, vb, acc[ni]);
      }
    }
  }

  // context write: D layout col(lane&15)=dh-sub, row(lg*4+r)=q-sub
  const int qrow = q0 + wave * 16 + lg * 4;
#pragma unroll
  for (int ni = 0; ni < 4; ++ni) {
    const int dh = ni * 16 + lq;
#pragma unroll
    for (int r = 0; r < 4; ++r) {
      out_ctx[(size_t)(b * 2048 + qrow + r) * 1024 + h * 64 + dh] = acc[ni][r];
    }
  }

  __syncthreads();
  for (int i = tid; i < 2048; i += 256) {
    atomicAdd(&out_cs[b * 2048 + i], cs_lds[i]);
  }
}

// ---------- launch ----------
extern "C" void kernel_launch(void* const* d_in, const int* in_sizes, int n_in,
                              void* d_out, int out_size, void* d_ws, size_t ws_size,
                              hipStream_t stream) {
  (void)in_sizes; (void)n_in; (void)out_size; (void)ws_size;
  const float* X    = (const float*)d_in[0];
  const float* mask = (const float*)d_in[1];
  const float* Wq   = (const float*)d_in[2];
  const float* bq   = (const float*)d_in[3];
  const float* Wk   = (const float*)d_in[4];
  const float* bk   = (const float*)d_in[5];
  const float* Wv   = (const float*)d_in[6];
  const float* bv   = (const float*)d_in[7];
  float* out = (float*)d_out;

  char* ws = (char*)d_ws;
  u16* Xb   = (u16*)(ws);                  // 4096*1024*2   = 8 MiB
  u16* Wcat = (u16*)(ws + 8388608);        // 3072*1024*2   = 6 MiB
  u16* Qb   = (u16*)(ws + 14680064);       // 8 MiB each
  u16* Kb   = (u16*)(ws + 23068672);
  u16* Vb   = (u16*)(ws + 31457280);       // end 39845888

  // casts
  cast_f32_bf16<<<4096, 256, 0, stream>>>(X, Xb, 1048576);
  cast_f32_bf16<<<1024, 256, 0, stream>>>(Wq, Wcat, 262144);
  cast_f32_bf16<<<1024, 256, 0, stream>>>(Wk, Wcat + 1048576, 262144);
  cast_f32_bf16<<<1024, 256, 0, stream>>>(Wv, Wcat + 2097152, 262144);

  // zero the colsum region of d_out (context region is fully overwritten)
  hipMemsetAsync(out + 4194304, 0, 4096 * sizeof(float), stream);

  // fused QKV projection: M=4096, N=3072, K=1024
  gemm_qkv<<<dim3(24, 32), 256, 0, stream>>>(Xb, Wcat, bq, bk, bv, Qb, Kb, Vb);

  // attention: 32 q-tiles x 32 (b,h)
  attn_kernel<<<dim3(32, 32), 256, 0, stream>>>(Qb, Kb, Vb, mask, out, out + 4194304);
}

// Round 2
// 205.262 us; speedup vs baseline: 1.5802x; 1.5802x over previous
//
#include <hip/hip_runtime.h>
#include <hip/hip_bf16.h>
#include <stdint.h>

typedef unsigned short u16;
typedef __attribute__((ext_vector_type(8))) unsigned short u16x8;
typedef __attribute__((ext_vector_type(4))) unsigned short u16x4;
typedef __attribute__((ext_vector_type(8))) __bf16 bf16x8;
typedef __attribute__((ext_vector_type(4))) float f32x4;

// ---------- helpers ----------
__device__ __forceinline__ f32x4 mfma16(u16x8 a, u16x8 b, f32x4 c) {
  return __builtin_amdgcn_mfma_f32_16x16x32_bf16(
      __builtin_bit_cast(bf16x8, a), __builtin_bit_cast(bf16x8, b), c, 0, 0, 0);
}

__device__ __forceinline__ u16 f2bf(float f) {
  unsigned u = __builtin_bit_cast(unsigned, f);
  return (u16)((u + 0x7fffu + ((u >> 16) & 1u)) >> 16);
}

__device__ __forceinline__ void gload_lds16(const void* g, void* l) {
  __builtin_amdgcn_global_load_lds(
      (__attribute__((address_space(1))) void*)const_cast<void*>(g),
      (__attribute__((address_space(3))) void*)l, 16, 0, 0);
}

#define SWZ(row, colbyte) ((((row) * 128) + (colbyte)) ^ (((row) & 7) << 4))

// ---------- fp32 -> bf16 cast ----------
__global__ void cast_f32_bf16(const float* __restrict__ src, u16* __restrict__ dst, int n4) {
  int i = blockIdx.x * blockDim.x + threadIdx.x;
  if (i < n4) {
    f32x4 v = ((const f32x4*)src)[i];
    u16x4 o;
    o[0] = f2bf(v[0]); o[1] = f2bf(v[1]); o[2] = f2bf(v[2]); o[3] = f2bf(v[3]);
    ((u16x4*)dst)[i] = o;
  }
}

// ---------- fused QKV GEMM ----------
// A: Xb [4096][1024] bf16.  Bm: Wcat [3072][1024] bf16 (rows = output features).
// Q/K: [B,H,S,Dh] bf16 (Q pre-scaled 0.125).  V: transposed [B,H,Dh,S] bf16.
__global__ __launch_bounds__(256) void gemm_qkv(
    const u16* __restrict__ A, const u16* __restrict__ Bm,
    const float* __restrict__ bq, const float* __restrict__ bk, const float* __restrict__ bv,
    u16* __restrict__ Qb, u16* __restrict__ Kb, u16* __restrict__ VTb) {
  __shared__ __align__(16) u16 Asm[128 * 32];
  __shared__ __align__(16) u16 Bsm[128 * 32];
  const int tid = threadIdx.x;
  const int wave = tid >> 6, lane = tid & 63;
  const int lq = lane & 15, lg = lane >> 4;
  const int wr = wave >> 1, wc = wave & 1;
  const int m0 = blockIdx.y * 128, n0 = blockIdx.x * 128;

  f32x4 zero = {0.f, 0.f, 0.f, 0.f};
  f32x4 acc[4][4];
#pragma unroll
  for (int mi = 0; mi < 4; ++mi)
#pragma unroll
    for (int ni = 0; ni < 4; ++ni) acc[mi][ni] = zero;

  for (int kt = 0; kt < 32; ++kt) {
    const int k0 = kt * 32;
    __syncthreads();
#pragma unroll
    for (int c = 0; c < 2; ++c) {
      const int idx = wave * 2 + c;
      const u16* ga = A + (size_t)(m0 + idx * 16 + (lane >> 2)) * 1024 + k0 + (lane & 3) * 8;
      gload_lds16(ga, (char*)Asm + idx * 1024);
      const u16* gb = Bm + (size_t)(n0 + idx * 16 + (lane >> 2)) * 1024 + k0 + (lane & 3) * 8;
      gload_lds16(gb, (char*)Bsm + idx * 1024);
    }
    __syncthreads();

    u16x8 af[4], bfr[4];
#pragma unroll
    for (int mi = 0; mi < 4; ++mi)
      af[mi] = *(const u16x8*)&Asm[(wr * 64 + mi * 16 + lq) * 32 + lg * 8];
#pragma unroll
    for (int ni = 0; ni < 4; ++ni)
      bfr[ni] = *(const u16x8*)&Bsm[(wc * 64 + ni * 16 + lq) * 32 + lg * 8];
#pragma unroll
    for (int mi = 0; mi < 4; ++mi)
#pragma unroll
      for (int ni = 0; ni < 4; ++ni)
        acc[mi][ni] = mfma16(af[mi], bfr[ni], acc[mi][ni]);
  }

  const int which = n0 >> 10;  // 0=Q, 1=K, 2=V (uniform per block)
  const float* bias = (which == 0) ? bq : ((which == 1) ? bk : bv);
  const float scl = (which == 0) ? 0.125f : 1.0f;
#pragma unroll
  for (int mi = 0; mi < 4; ++mi) {
    const int m = m0 + wr * 64 + mi * 16 + lg * 4;
    const int bb = m >> 11;
    const int s = m & 2047;
#pragma unroll
    for (int ni = 0; ni < 4; ++ni) {
      const int n = n0 + wc * 64 + ni * 16 + lq;
      const int d = n & 1023;
      const int h = d >> 6, dh = d & 63;
      const float bi = bias[d];
#pragma unroll
      for (int r = 0; r < 4; ++r) {
        float v = (acc[mi][ni][r] + bi) * scl;
        if (which == 2)
          VTb[(((size_t)bb * 16 + h) * 64 + dh) * 2048 + (size_t)(s + r)] = f2bf(v);
        else {
          u16* dst = (which == 0) ? Qb : Kb;
          dst[(((size_t)bb * 16 + h) * 2048 + (size_t)(s + r)) * 64 + dh] = f2bf(v);
        }
      }
    }
  }
}

// ---------- attention ----------
// 512 threads = 8 waves; q-tile 128 (16 q-rows per wave); k-tile 64, double-buffered.
// Pass1 (swapped mfma -> per-q stats in-lane), pass2 (standard mfma -> cheap colsum).
__global__ __launch_bounds__(512, 4) void attn_kernel(
    const u16* __restrict__ Qb, const u16* __restrict__ Kb, const u16* __restrict__ VTb,
    const float* __restrict__ maskg, float* __restrict__ out_ctx, float* __restrict__ out_cs) {
  __shared__ __align__(16) u16 Kl[2][4096];
  __shared__ __align__(16) u16 VTl[2][4096];
  __shared__ __align__(16) u16 Pl[8 * 1024];   // per-wave 16x64 bf16 (2KB each)
  __shared__ float sml[128], sil[128];
  __shared__ float cs_lds[2048];

  const int tid = threadIdx.x;
  const int w = tid >> 6, lane = tid & 63;
  const int lq = lane & 15, lg = lane >> 4;
  // bijective XCD swizzle: 512 blocks = 8 XCDs x 64; same-bh blocks share an XCD L2
  const int bid = (blockIdx.x & 7) * 64 + (blockIdx.x >> 3);
  const int qt = bid & 15, bh = bid >> 4;
  const int b = bh >> 4, h = bh & 15;
  const int q0 = qt * 128;

  for (int i = tid; i < 2048; i += 512) cs_lds[i] = 0.f;

  const u16* qp = Qb + ((size_t)bh * 2048 + q0 + w * 16 + lq) * 64 + lg * 8;
  const u16x8 qa0 = *(const u16x8*)qp;
  const u16x8 qa1 = *(const u16x8*)(qp + 32);

  const char* Kbase = (const char*)(Kb + (size_t)bh * 2048 * 64);
  const char* VTbase = (const char*)(VTb + (size_t)bh * 64 * 2048);
  const float* mbase = maskg + b * 2048;

  // staging: thread covers 16B chunk (w*64+lane); pre-swizzled global source,
  // linear LDS dest (wave-uniform base + lane*16) -> swizzled reads are conflict-free
  const int mchunk = w * 64 + lane;
  const int srow = mchunk >> 3;
  const int scol = ((mchunk & 7) * 16) ^ ((srow & 7) << 4);
  char* kb0 = (char*)&Kl[0][0] + w * 1024;
  char* kb1 = (char*)&Kl[1][0] + w * 1024;
  char* vb0 = (char*)&VTl[0][0] + w * 1024;
  char* vb1 = (char*)&VTl[1][0] + w * 1024;

  auto stageK = [&](int kt, int buf) {
    gload_lds16(Kbase + (size_t)(kt * 64 + srow) * 128 + scol, buf ? kb1 : kb0);
  };
  auto stageVT = [&](int kt, int buf) {
    gload_lds16(VTbase + (size_t)srow * 4096 + (size_t)kt * 128 + scol, buf ? vb1 : vb0);
  };

  // ---- pass 1: row max + denominator (swapped: D[k][q], q = lq in-lane) ----
  float m_l = -3.0e38f, l_l = 0.f;
  stageK(0, 0);
  __syncthreads();
  for (int kt = 0; kt < 32; ++kt) {
    const int cur = kt & 1;
    if (kt + 1 < 32) stageK(kt + 1, cur ^ 1);
    const char* Kt = (const char*)&Kl[cur][0];
#pragma unroll
    for (int chunk = 0; chunk < 4; ++chunk) {
      const int krow = chunk * 16 + lq;
      u16x8 ka0 = *(const u16x8*)(Kt + SWZ(krow, lg * 16));
      u16x8 ka1 = *(const u16x8*)(Kt + SWZ(krow, 64 + lg * 16));
      f32x4 s = {0.f, 0.f, 0.f, 0.f};
      s = mfma16(ka0, qa0, s);
      s = mfma16(ka1, qa1, s);
      f32x4 mv = *(const f32x4*)(mbase + kt * 64 + chunk * 16 + lg * 4);
      const float s0 = s[0] + mv[0], s1 = s[1] + mv[1];
      const float s2 = s[2] + mv[2], s3 = s[3] + mv[3];
      const float cmax = fmaxf(fmaxf(s0, s1), fmaxf(s2, s3));
      const float mn = fmaxf(m_l, cmax);
      l_l = l_l * __expf(m_l - mn) +
            __expf(s0 - mn) + __expf(s1 - mn) + __expf(s2 - mn) + __expf(s3 - mn);
      m_l = mn;
    }
    __syncthreads();
  }
#pragma unroll
  for (int off = 16; off <= 32; off <<= 1) {
    const float mo = __shfl_xor(m_l, off);
    const float lo = __shfl_xor(l_l, off);
    const float mn = fmaxf(m_l, mo);
    l_l = l_l * __expf(m_l - mn) + lo * __expf(mo - mn);
    m_l = mn;
  }
  // publish per-q stats (wave-local region; no barrier needed)
  sml[w * 16 + lq] = m_l;
  sil[w * 16 + lq] = 1.0f / l_l;
  const f32x4 m4 = *(const f32x4*)&sml[w * 16 + lg * 4];   // q-sub = lg*4 + r
  const f32x4 il4 = *(const f32x4*)&sil[w * 16 + lg * 4];

  // ---- pass 2: exact probs -> colsum + PV (standard: D[q][k]) ----
  f32x4 acc[4];
  {
    f32x4 zero = {0.f, 0.f, 0.f, 0.f};
#pragma unroll
    for (int ni = 0; ni < 4; ++ni) acc[ni] = zero;
  }
  char* Pw = (char*)Pl + w * 2048;

  stageK(0, 0);
  stageVT(0, 0);
  __syncthreads();
  for (int kt = 0; kt < 32; ++kt) {
    const int cur = kt & 1;
    if (kt + 1 < 32) { stageK(kt + 1, cur ^ 1); stageVT(kt + 1, cur ^ 1); }
    const char* Kt = (const char*)&Kl[cur][0];
    const char* Vt = (const char*)&VTl[cur][0];
#pragma unroll
    for (int chunk = 0; chunk < 4; ++chunk) {
      const int krow = chunk * 16 + lq;
      u16x8 ka0 = *(const u16x8*)(Kt + SWZ(krow, lg * 16));
      u16x8 ka1 = *(const u16x8*)(Kt + SWZ(krow, 64 + lg * 16));
      f32x4 s = {0.f, 0.f, 0.f, 0.f};
      s = mfma16(qa0, ka0, s);   // D[q=lg*4+r][k=krow]
      s = mfma16(qa1, ka1, s);
      const float mvk = mbase[kt * 64 + krow];  // uniform over r
      const float p0 = __expf(s[0] + mvk - m4[0]) * il4[0];
      const float p1 = __expf(s[1] + mvk - m4[1]) * il4[1];
      const float p2 = __expf(s[2] + mvk - m4[2]) * il4[2];
      const float p3 = __expf(s[3] + mvk - m4[3]) * il4[3];

      float csum = (p0 + p1) + (p2 + p3);
      csum += __shfl_xor(csum, 16);
      csum += __shfl_xor(csum, 32);
      if (lg == 0) atomicAdd(&cs_lds[kt * 64 + krow], csum);

      const int cbyte = chunk * 32 + lq * 2;   // col k = chunk*16 + lq
      *(u16*)(Pw + SWZ(lg * 4 + 0, cbyte)) = f2bf(p0);
      *(u16*)(Pw + SWZ(lg * 4 + 1, cbyte)) = f2bf(p1);
      *(u16*)(Pw + SWZ(lg * 4 + 2, cbyte)) = f2bf(p2);
      *(u16*)(Pw + SWZ(lg * 4 + 3, cbyte)) = f2bf(p3);
    }
    // PV: ctx[q][dh] += P[q][k] * VT[dh][k]^T
#pragma unroll
    for (int kc = 0; kc < 2; ++kc) {
      u16x8 pa = *(const u16x8*)(Pw + SWZ(lq, kc * 64 + lg * 16));
#pragma unroll
      for (int ni = 0; ni < 4; ++ni) {
        u16x8 vb = *(const u16x8*)(Vt + SWZ(ni * 16 + lq, kc * 64 + lg * 16));
        acc[ni] = mfma16(pa, vb, acc[ni]);
      }
    }
    __syncthreads();
  }

  // context write: D rows = q (lg*4+r), cols = dh (ni*16+lq)
  const int qrow = q0 + w * 16 + lg * 4;
#pragma unroll
  for (int ni = 0; ni < 4; ++ni) {
    const int dh = ni * 16 + lq;
#pragma unroll
    for (int r = 0; r < 4; ++r)
      out_ctx[(size_t)(b * 2048 + qrow + r) * 1024 + h * 64 + dh] = acc[ni][r];
  }

  __syncthreads();
  for (int i = tid; i < 2048; i += 512)
    atomicAdd(&out_cs[b * 2048 + i], cs_lds[i]);
}

// ---------- launch ----------
extern "C" void kernel_launch(void* const* d_in, const int* in_sizes, int n_in,
                              void* d_out, int out_size, void* d_ws, size_t ws_size,
                              hipStream_t stream) {
  (void)in_sizes; (void)n_in; (void)out_size; (void)ws_size;
  const float* X    = (const float*)d_in[0];
  const float* mask = (const float*)d_in[1];
  const float* Wq   = (const float*)d_in[2];
  const float* bq   = (const float*)d_in[3];
  const float* Wk   = (const float*)d_in[4];
  const float* bk   = (const float*)d_in[5];
  const float* Wv   = (const float*)d_in[6];
  const float* bv   = (const float*)d_in[7];
  float* out = (float*)d_out;

  char* ws = (char*)d_ws;
  u16* Xb   = (u16*)(ws);                  // 4096*1024*2 = 8 MiB
  u16* Wcat = (u16*)(ws + 8388608);        // 3072*1024*2 = 6 MiB
  u16* Qb   = (u16*)(ws + 14680064);       // 8 MiB
  u16* Kb   = (u16*)(ws + 23068672);       // 8 MiB
  u16* VTb  = (u16*)(ws + 31457280);       // 8 MiB (transposed V)

  cast_f32_bf16<<<4096, 256, 0, stream>>>(X, Xb, 1048576);
  cast_f32_bf16<<<1024, 256, 0, stream>>>(Wq, Wcat, 262144);
  cast_f32_bf16<<<1024, 256, 0, stream>>>(Wk, Wcat + 1048576, 262144);
  cast_f32_bf16<<<1024, 256, 0, stream>>>(Wv, Wcat + 2097152, 262144);

  hipMemsetAsync(out + 4194304, 0, 4096 * sizeof(float), stream);

  gemm_qkv<<<dim3(24, 32), 256, 0, stream>>>(Xb, Wcat, bq, bk, bv, Qb, Kb, VTb);

  attn_kernel<<<512, 512, 0, stream>>>(Qb, Kb, VTb, mask, out, out + 4194304);
}

// Round 3
// 156.494 us; speedup vs baseline: 2.0727x; 1.3116x over previous
//
#include <hip/hip_runtime.h>
#include <hip/hip_bf16.h>
#include <stdint.h>

typedef unsigned short u16;
typedef __attribute__((ext_vector_type(8))) unsigned short u16x8;
typedef __attribute__((ext_vector_type(4))) unsigned short u16x4;
typedef __attribute__((ext_vector_type(8))) __bf16 bf16x8;
typedef __attribute__((ext_vector_type(4))) float f32x4;

#define LOG2E 1.44269504088896340736f

#if defined(__has_builtin)
#if __has_builtin(__builtin_amdgcn_exp2f)
#define EXP2(x) __builtin_amdgcn_exp2f(x)
#endif
#endif
#ifndef EXP2
#define EXP2(x) exp2f(x)
#endif

// ---------- helpers ----------
__device__ __forceinline__ f32x4 mfma16(u16x8 a, u16x8 b, f32x4 c) {
  return __builtin_amdgcn_mfma_f32_16x16x32_bf16(
      __builtin_bit_cast(bf16x8, a), __builtin_bit_cast(bf16x8, b), c, 0, 0, 0);
}

__device__ __forceinline__ u16 f2bf(float f) {
  unsigned u = __builtin_bit_cast(unsigned, f);
  return (u16)((u + 0x7fffu + ((u >> 16) & 1u)) >> 16);
}

// pack two f32 -> two bf16 in one u32 (low = a, high = b), RNE
__device__ __forceinline__ unsigned cvtpk(float a, float b) {
  unsigned r;
  asm volatile("v_cvt_pk_bf16_f32 %0, %1, %2" : "=v"(r) : "v"(a), "v"(b));
  return r;
}

__device__ __forceinline__ void gload_lds16(const void* g, void* l) {
  __builtin_amdgcn_global_load_lds(
      (__attribute__((address_space(1))) void*)const_cast<void*>(g),
      (__attribute__((address_space(3))) void*)l, 16, 0, 0);
}

#define SWZ(row, colbyte) ((((row) * 128) + (colbyte)) ^ (((row) & 7) << 4))

// ---------- fp32 -> bf16 cast ----------
__global__ void cast_f32_bf16(const float* __restrict__ src, u16* __restrict__ dst, int n4) {
  int i = blockIdx.x * blockDim.x + threadIdx.x;
  if (i < n4) {
    f32x4 v = ((const f32x4*)src)[i];
    u16x4 o;
    o[0] = f2bf(v[0]); o[1] = f2bf(v[1]); o[2] = f2bf(v[2]); o[3] = f2bf(v[3]);
    ((u16x4*)dst)[i] = o;
  }
}

// ---------- fused QKV GEMM ----------
// Q pre-scaled by 0.125*log2e so attention exps are raw v_exp_f32 (2^x).
__global__ __launch_bounds__(256) void gemm_qkv(
    const u16* __restrict__ A, const u16* __restrict__ Bm,
    const float* __restrict__ bq, const float* __restrict__ bk, const float* __restrict__ bv,
    u16* __restrict__ Qb, u16* __restrict__ Kb, u16* __restrict__ VTb) {
  __shared__ __align__(16) u16 Asm[128 * 32];
  __shared__ __align__(16) u16 Bsm[128 * 32];
  const int tid = threadIdx.x;
  const int wave = tid >> 6, lane = tid & 63;
  const int lq = lane & 15, lg = lane >> 4;
  const int wr = wave >> 1, wc = wave & 1;
  const int m0 = blockIdx.y * 128, n0 = blockIdx.x * 128;

  f32x4 zero = {0.f, 0.f, 0.f, 0.f};
  f32x4 acc[4][4];
#pragma unroll
  for (int mi = 0; mi < 4; ++mi)
#pragma unroll
    for (int ni = 0; ni < 4; ++ni) acc[mi][ni] = zero;

  for (int kt = 0; kt < 32; ++kt) {
    const int k0 = kt * 32;
    __syncthreads();
#pragma unroll
    for (int c = 0; c < 2; ++c) {
      const int idx = wave * 2 + c;
      const u16* ga = A + (size_t)(m0 + idx * 16 + (lane >> 2)) * 1024 + k0 + (lane & 3) * 8;
      gload_lds16(ga, (char*)Asm + idx * 1024);
      const u16* gb = Bm + (size_t)(n0 + idx * 16 + (lane >> 2)) * 1024 + k0 + (lane & 3) * 8;
      gload_lds16(gb, (char*)Bsm + idx * 1024);
    }
    __syncthreads();

    u16x8 af[4], bfr[4];
#pragma unroll
    for (int mi = 0; mi < 4; ++mi)
      af[mi] = *(const u16x8*)&Asm[(wr * 64 + mi * 16 + lq) * 32 + lg * 8];
#pragma unroll
    for (int ni = 0; ni < 4; ++ni)
      bfr[ni] = *(const u16x8*)&Bsm[(wc * 64 + ni * 16 + lq) * 32 + lg * 8];
#pragma unroll
    for (int mi = 0; mi < 4; ++mi)
#pragma unroll
      for (int ni = 0; ni < 4; ++ni)
        acc[mi][ni] = mfma16(af[mi], bfr[ni], acc[mi][ni]);
  }

  const int which = n0 >> 10;  // 0=Q, 1=K, 2=V (uniform per block)
  const float* bias = (which == 0) ? bq : ((which == 1) ? bk : bv);
  const float scl = (which == 0) ? (0.125f * LOG2E) : 1.0f;
#pragma unroll
  for (int mi = 0; mi < 4; ++mi) {
    const int m = m0 + wr * 64 + mi * 16 + lg * 4;
    const int bb = m >> 11;
    const int s = m & 2047;
#pragma unroll
    for (int ni = 0; ni < 4; ++ni) {
      const int n = n0 + wc * 64 + ni * 16 + lq;
      const int d = n & 1023;
      const int h = d >> 6, dh = d & 63;
      const float bi = bias[d];
#pragma unroll
      for (int r = 0; r < 4; ++r) {
        float v = (acc[mi][ni][r] + bi) * scl;
        if (which == 2)
          VTb[(((size_t)bb * 16 + h) * 64 + dh) * 2048 + (size_t)(s + r)] = f2bf(v);
        else {
          u16* dst = (which == 0) ? Qb : Kb;
          dst[(((size_t)bb * 16 + h) * 2048 + (size_t)(s + r)) * 64 + dh] = f2bf(v);
        }
      }
    }
  }
}

// ---------- kernel A: fused attention, single pass, m=0 softmax ----------
// 512 thr = 8 waves, each wave owns 32 q rows (q-tile 256). K/VT double-buffered.
// Swapped QK^T (D[k][q]) -> l per q is lane-local; P packed via cvt_pk into LDS;
// PV standard -> D[q][dh]; normalize context by 1/l in the epilogue.
__global__ __launch_bounds__(512) void attn_fused(
    const u16* __restrict__ Qb, const u16* __restrict__ Kb, const u16* __restrict__ VTb,
    const float* __restrict__ maskg, float* __restrict__ out_ctx, float* __restrict__ winv) {
  __shared__ __align__(16) u16 Kl[2][4096];   // 16 KB
  __shared__ __align__(16) u16 VTl[2][4096];  // 16 KB
  __shared__ __align__(16) u16 Pl[8][2048];   // 32 KB: per-wave 32q x 64k bf16

  const int tid = threadIdx.x;
  const int w = tid >> 6, lane = tid & 63;
  const int lq = lane & 15, lg = lane >> 4;
  // XCD swizzle: 256 blocks -> each XCD gets 4 consecutive bh (32 blocks)
  const int bid = (blockIdx.x & 7) * 32 + (blockIdx.x >> 3);
  const int qt = bid & 7, bh = bid >> 3;
  const int b = bh >> 4, h = bh & 15;
  const int qw = qt * 256 + w * 32;  // wave's first q row

  // Q fragments: lane holds Q[qw + (qgrp*16) + lq][dh 8lg..]
  const u16* qp0 = Qb + ((size_t)bh * 2048 + qw + lq) * 64 + lg * 8;
  const u16* qp1 = qp0 + 16 * 64;
  const u16x8 qa00 = *(const u16x8*)qp0, qa01 = *(const u16x8*)(qp0 + 32);
  const u16x8 qa10 = *(const u16x8*)qp1, qa11 = *(const u16x8*)(qp1 + 32);

  const char* Kbase = (const char*)(Kb + (size_t)bh * 2048 * 64);
  const char* VTbase = (const char*)(VTb + (size_t)bh * 64 * 2048);
  const float* mbase = maskg + b * 2048;

  const int srow = tid >> 3;
  const int scol = ((tid & 7) * 16) ^ ((srow & 7) << 4);
  char* kb0 = (char*)&Kl[0][0] + w * 1024;
  char* kb1 = (char*)&Kl[1][0] + w * 1024;
  char* vb0 = (char*)&VTl[0][0] + w * 1024;
  char* vb1 = (char*)&VTl[1][0] + w * 1024;

  auto stageK = [&](int kt, int buf) {
    gload_lds16(Kbase + (size_t)(kt * 64 + srow) * 128 + scol, buf ? kb1 : kb0);
  };
  auto stageVT = [&](int kt, int buf) {
    gload_lds16(VTbase + (size_t)srow * 4096 + (size_t)kt * 128 + scol, buf ? vb1 : vb0);
  };

  f32x4 acc[2][4];
  {
    f32x4 zero = {0.f, 0.f, 0.f, 0.f};
#pragma unroll
    for (int g = 0; g < 2; ++g)
#pragma unroll
      for (int ni = 0; ni < 4; ++ni) acc[g][ni] = zero;
  }
  float l_lo = 0.f, l_hi = 0.f;
  char* Pw = (char*)&Pl[w][0];

  stageK(0, 0);
  stageVT(0, 0);
  __syncthreads();
  for (int kt = 0; kt < 32; ++kt) {
    const int cur = kt & 1;
    if (kt + 1 < 32) { stageK(kt + 1, cur ^ 1); stageVT(kt + 1, cur ^ 1); }
    const char* Kt = (const char*)&Kl[cur][0];
    const char* Vt = (const char*)&VTl[cur][0];

#pragma unroll
    for (int chunk = 0; chunk < 4; ++chunk) {
      const int krow = chunk * 16 + lq;
      const u16x8 ka0 = *(const u16x8*)(Kt + SWZ(krow, lg * 16));
      const u16x8 ka1 = *(const u16x8*)(Kt + SWZ(krow, 64 + lg * 16));
      f32x4 z = {0.f, 0.f, 0.f, 0.f};
      f32x4 slo = mfma16(ka0, qa00, z);
      slo = mfma16(ka1, qa01, slo);
      f32x4 shi = mfma16(ka0, qa10, z);
      shi = mfma16(ka1, qa11, shi);
      // mask (per k = chunk*16+lg*4+r), folded to log2 domain
      const f32x4 mv = *(const f32x4*)(mbase + kt * 64 + chunk * 16 + lg * 4);
      const float m0 = mv[0] * LOG2E, m1 = mv[1] * LOG2E;
      const float m2 = mv[2] * LOG2E, m3 = mv[3] * LOG2E;
      const float pl0 = EXP2(slo[0] + m0), pl1 = EXP2(slo[1] + m1);
      const float pl2 = EXP2(slo[2] + m2), pl3 = EXP2(slo[3] + m3);
      const float ph0 = EXP2(shi[0] + m0), ph1 = EXP2(shi[1] + m1);
      const float ph2 = EXP2(shi[2] + m2), ph3 = EXP2(shi[3] + m3);
      l_lo += (pl0 + pl1) + (pl2 + pl3);
      l_hi += (ph0 + ph1) + (ph2 + ph3);
      // P[q][k]: row = qgrp*16+lq, 4 consecutive k -> one b64 write
      uint2 wlo, whi;
      wlo.x = cvtpk(pl0, pl1); wlo.y = cvtpk(pl2, pl3);
      whi.x = cvtpk(ph0, ph1); whi.y = cvtpk(ph2, ph3);
      *(uint2*)(Pw + SWZ(lq, chunk * 32 + lg * 8)) = wlo;
      *(uint2*)(Pw + SWZ(16 + lq, chunk * 32 + lg * 8)) = whi;
    }

    // PV: ctx[q][dh] += P[q][k] * VT[dh][k]^T
#pragma unroll
    for (int kc = 0; kc < 2; ++kc) {
      const u16x8 pa0 = *(const u16x8*)(Pw + SWZ(lq, kc * 64 + lg * 16));
      const u16x8 pa1 = *(const u16x8*)(Pw + SWZ(16 + lq, kc * 64 + lg * 16));
#pragma unroll
      for (int ni = 0; ni < 4; ++ni) {
        const u16x8 vb = *(const u16x8*)(Vt + SWZ(ni * 16 + lq, kc * 64 + lg * 16));
        acc[0][ni] = mfma16(pa0, vb, acc[0][ni]);
        acc[1][ni] = mfma16(pa1, vb, acc[1][ni]);
      }
    }
    __syncthreads();
  }

  // reduce l over the 4 lg-groups (each covered distinct k)
  l_lo += __shfl_xor(l_lo, 16); l_lo += __shfl_xor(l_lo, 32);
  l_hi += __shfl_xor(l_hi, 16); l_hi += __shfl_xor(l_hi, 32);
  const float il_lo = 1.0f / l_lo;
  const float il_hi = 1.0f / l_hi;
  if (lg == 0) {
    winv[bh * 2048 + qw + lq] = il_lo;
    winv[bh * 2048 + qw + 16 + lq] = il_hi;
  }
  // redistribute 1/l to the PV output layout (rows q-sub = lg*4+r)
  f32x4 il4[2];
#pragma unroll
  for (int r = 0; r < 4; ++r) {
    il4[0][r] = __shfl(il_lo, lg * 4 + r);
    il4[1][r] = __shfl(il_hi, lg * 4 + r);
  }
#pragma unroll
  for (int g = 0; g < 2; ++g) {
    const int qrow = b * 2048 + qw + g * 16 + lg * 4;
#pragma unroll
    for (int ni = 0; ni < 4; ++ni) {
      const int dh = h * 64 + ni * 16 + lq;
#pragma unroll
      for (int r = 0; r < 4; ++r)
        out_ctx[(size_t)(qrow + r) * 1024 + dh] = acc[g][ni][r] * il4[g][r];
    }
  }
}

// ---------- kernel B: prob column sums ----------
// Block owns 128 k rows (K frags in regs); streams Q tiles through LDS.
// c_k = sum_q exp2(s+mask*L) * inv_l_q, atomically added into out_cs[b][k].
__global__ __launch_bounds__(512) void colsum_kernel(
    const u16* __restrict__ Qb, const u16* __restrict__ Kb,
    const float* __restrict__ maskg, const float* __restrict__ winv,
    float* __restrict__ out_cs) {
  __shared__ __align__(16) u16 Ql[2][4096];  // 16 KB

  const int tid = threadIdx.x;
  const int w = tid >> 6, lane = tid & 63;
  const int lq = lane & 15, lg = lane >> 4;
  const int bid = (blockIdx.x & 7) * 64 + (blockIdx.x >> 3);
  const int ktile = bid & 15, bh = bid >> 4;
  const int b = bh >> 4;
  const int kbase = ktile * 128 + w * 16;

  const u16* kp = Kb + ((size_t)bh * 2048 + kbase + lq) * 64 + lg * 8;
  const u16x8 kb0 = *(const u16x8*)kp, kb1 = *(const u16x8*)(kp + 32);
  const float mvl = maskg[b * 2048 + kbase + lq] * LOG2E;
  const float* wbase = winv + bh * 2048;
  const char* Qbase = (const char*)(Qb + (size_t)bh * 2048 * 64);

  const int srow = tid >> 3;
  const int scol = ((tid & 7) * 16) ^ ((srow & 7) << 4);
  char* qd0 = (char*)&Ql[0][0] + w * 1024;
  char* qd1 = (char*)&Ql[1][0] + w * 1024;
  auto stageQ = [&](int qt, int buf) {
    gload_lds16(Qbase + (size_t)(qt * 64 + srow) * 128 + scol, buf ? qd1 : qd0);
  };

  float c = 0.f;
  stageQ(0, 0);
  __syncthreads();
  for (int qt = 0; qt < 32; ++qt) {
    const int cur = qt & 1;
    if (qt + 1 < 32) stageQ(qt + 1, cur ^ 1);
    const char* Qt = (const char*)&Ql[cur][0];
#pragma unroll
    for (int chunk = 0; chunk < 4; ++chunk) {
      const u16x8 qf0 = *(const u16x8*)(Qt + SWZ(chunk * 16 + lq, lg * 16));
      const u16x8 qf1 = *(const u16x8*)(Qt + SWZ(chunk * 16 + lq, 64 + lg * 16));
      f32x4 z = {0.f, 0.f, 0.f, 0.f};
      f32x4 s = mfma16(qf0, kb0, z);   // D[q = chunk*16+lg*4+r][k = kbase+lq]
      s = mfma16(qf1, kb1, s);
      const f32x4 wv = *(const f32x4*)(wbase + qt * 64 + chunk * 16 + lg * 4);
      c += EXP2(s[0] + mvl) * wv[0] + EXP2(s[1] + mvl) * wv[1] +
           EXP2(s[2] + mvl) * wv[2] + EXP2(s[3] + mvl) * wv[3];
    }
    __syncthreads();
  }
  c += __shfl_xor(c, 16);
  c += __shfl_xor(c, 32);
  if (lg == 0) atomicAdd(&out_cs[b * 2048 + kbase + lq], c);
}

// ---------- launch ----------
extern "C" void kernel_launch(void* const* d_in, const int* in_sizes, int n_in,
                              void* d_out, int out_size, void* d_ws, size_t ws_size,
                              hipStream_t stream) {
  (void)in_sizes; (void)n_in; (void)out_size; (void)ws_size;
  const float* X    = (const float*)d_in[0];
  const float* mask = (const float*)d_in[1];
  const float* Wq   = (const float*)d_in[2];
  const float* bq   = (const float*)d_in[3];
  const float* Wk   = (const float*)d_in[4];
  const float* bk   = (const float*)d_in[5];
  const float* Wv   = (const float*)d_in[6];
  const float* bv   = (const float*)d_in[7];
  float* out = (float*)d_out;

  char* ws = (char*)d_ws;
  u16* Xb   = (u16*)(ws);                  // 8 MiB (consumed by GEMM)
  u16* Wcat = (u16*)(ws + 8388608);        // 6 MiB
  u16* Qb   = (u16*)(ws + 14680064);       // 8 MiB
  u16* Kb   = (u16*)(ws + 23068672);       // 8 MiB
  u16* VTb  = (u16*)(ws + 31457280);       // 8 MiB (transposed V)
  // winv overlaps Xb: Xb is dead after gemm_qkv, winv written by attn_fused after it
  float* winv = (float*)ws;                // 256 KiB

  cast_f32_bf16<<<4096, 256, 0, stream>>>(X, Xb, 1048576);
  cast_f32_bf16<<<1024, 256, 0, stream>>>(Wq, Wcat, 262144);
  cast_f32_bf16<<<1024, 256, 0, stream>>>(Wk, Wcat + 1048576, 262144);
  cast_f32_bf16<<<1024, 256, 0, stream>>>(Wv, Wcat + 2097152, 262144);

  hipMemsetAsync(out + 4194304, 0, 4096 * sizeof(float), stream);

  gemm_qkv<<<dim3(24, 32), 256, 0, stream>>>(Xb, Wcat, bq, bk, bv, Qb, Kb, VTb);

  attn_fused<<<256, 512, 0, stream>>>(Qb, Kb, VTb, mask, out, winv);
  colsum_kernel<<<512, 512, 0, stream>>>(Qb, Kb, mask, winv, out + 4194304);
}